// Round 4
// baseline (314.011 us; speedup 1.0000x reference)
//
#include <hip/hip_runtime.h>

// decoderHead: B=4, S=4096, E=512, DK=64, fp32 I/O.
constexpr int BB = 4;
constexpr int SS = 4096;
constexpr int EE = 512;
constexpr int BS = BB * SS;

typedef __attribute__((ext_vector_type(8))) short bf16x8;
typedef __attribute__((ext_vector_type(4))) float f32x4;
typedef unsigned long long ull;

union Frag {
  uint4 u4;
  unsigned int u[4];
  bf16x8 v;
};

__device__ __forceinline__ unsigned short f2bf(float f) {
  unsigned int u = __float_as_uint(f);
  unsigned int r = u + 0x7FFFu + ((u >> 16) & 1u);   // RNE
  return (unsigned short)(r >> 16);
}
__device__ __forceinline__ float bf2f(unsigned short h) {
  return __uint_as_float(((unsigned int)h) << 16);
}
__device__ __forceinline__ unsigned int cvtpk(float a, float b) {
  unsigned int r;
  asm("v_cvt_pk_bf16_f32 %0, %1, %2" : "=v"(r) : "v"(a), "v"(b));
  return r;  // lo = bf16(a), hi = bf16(b)
}
// global -> LDS direct (16B/lane). Dest wave-uniform base; src per-lane.
__device__ __forceinline__ void gl16(const unsigned short* g, unsigned int* l) {
  __builtin_amdgcn_global_load_lds(
      (const __attribute__((address_space(1))) unsigned int*)(size_t)g,
      (__attribute__((address_space(3))) unsigned int*)(unsigned int)(size_t)l,
      16, 0, 0);
}
#define WAITVM(n) asm volatile("s_waitcnt vmcnt(" #n ")" ::: "memory")

// split 8 fp32 -> hi bf16x8 (truncate) + lo bf16x8 (residual, truncate)
__device__ __forceinline__ void split8(const float* v, uint4& H, uint4& L) {
  unsigned int hu[4], lu[4];
#pragma unroll
  for (int i = 0; i < 4; ++i) {
    unsigned int u0 = __float_as_uint(v[2 * i]);
    unsigned int u1 = __float_as_uint(v[2 * i + 1]);
    unsigned int h0 = u0 & 0xFFFF0000u, h1 = u1 & 0xFFFF0000u;
    hu[i] = (u0 >> 16) | h1;
    unsigned int r0 = __float_as_uint(v[2 * i] - __uint_as_float(h0));
    unsigned int r1 = __float_as_uint(v[2 * i + 1] - __uint_as_float(h1));
    lu[i] = (r0 >> 16) | (r1 & 0xFFFF0000u);
  }
  H = make_uint4(hu[0], hu[1], hu[2], hu[3]);
  L = make_uint4(lu[0], lu[1], lu[2], lu[3]);
}

// ---------------------------------------------------------------------------
// mask_kernel: maskp[row] = any(x[row,:] != +-0)  (one wave per row)
// ---------------------------------------------------------------------------
__global__ __launch_bounds__(256) void mask_kernel(const float* __restrict__ x,
                                                   float* __restrict__ maskp) {
  const int row = blockIdx.x * 4 + (threadIdx.x >> 6);
  const int l = threadIdx.x & 63;
  const uint4* xr = (const uint4*)(x + (size_t)row * EE) + l;
  uint4 a = xr[0], b = xr[64];
  unsigned int o = (a.x | a.y | a.z | a.w | b.x | b.y | b.z | b.w) << 1;
  bool nz = __any(o != 0u);
  if (l == 0) maskp[row] = nz ? 1.0f : 0.0f;
}

// ---------------------------------------------------------------------------
// prep_w: transpose + hi/lo-split W -> Whl[mat][hl][n=64][k=512] bf16.
// Q-scale (log2(e)/8) folded into mat 0.
// ---------------------------------------------------------------------------
__global__ __launch_bounds__(256) void prep_w(
    const float* __restrict__ Wq, const float* __restrict__ Wk,
    const float* __restrict__ Wv, unsigned short* __restrict__ Whl) {
  const int m = blockIdx.x;            // 0..2
  const int ng = blockIdx.y;           // 0..15
  const int t = threadIdx.x;
  const int n = ng * 4 + (t >> 6);
  const int kl = t & 63;
  const float* W = (m == 0) ? Wq : (m == 1) ? Wk : Wv;
  const float sc = (m == 0) ? 0.18033688011112042f : 1.0f;
#pragma unroll
  for (int kc = 0; kc < 8; ++kc) {
    const int k = kc * 64 + kl;
    const float w = W[(size_t)k * 64 + n] * sc;
    const unsigned int hu = __float_as_uint(w) & 0xFFFF0000u;
    const float lo = w - __uint_as_float(hu);
    Whl[((size_t)(m * 2 + 0) * 64 + n) * 512 + k] = (unsigned short)(hu >> 16);
    Whl[((size_t)(m * 2 + 1) * 64 + n) * 512 + k] =
        (unsigned short)(__float_as_uint(lo) >> 16);
  }
}

// ---------------------------------------------------------------------------
// proj_kernel<KV>: register-only MFMA GEMM (no LDS, no barriers).
// KV=0: Q = (x@Wq'); KV=1: K = (ctx@Wk)*mask, V = (ctx@Wv)*mask -> Vt.
// Block 128 thr (2 waves x 16 rows). A-frag direct from global (reg dbuf);
// B-frags direct from pre-split Whl (L1-hot). 3-term hi/lo product.
// ---------------------------------------------------------------------------
template <int KV>
__global__ __launch_bounds__(128) void proj_kernel(
    const float* __restrict__ x, const float* __restrict__ ctx,
    const unsigned short* __restrict__ Whl, const float* __restrict__ maskp,
    unsigned short* __restrict__ Qb, unsigned short* __restrict__ Kb,
    unsigned short* __restrict__ Vt)
{
  const int t = threadIdx.x;
  const int l = t & 63, wi = t >> 6, g = l >> 4, li = l & 15;
  const int r0g = blockIdx.x * 32;
  const int row = r0g + wi * 16 + li;

  const float* A = KV ? ctx : x;
  const float* ap = A + (size_t)row * EE + g * 8;

  f32x4 acc[KV ? 8 : 4] = {};
  float a8[8];
  *(float4*)&a8[0] = *(const float4*)(ap);
  *(float4*)&a8[4] = *(const float4*)(ap + 4);

  for (int c = 0; c < 16; ++c) {
    uint4 H, L;
    split8(a8, H, L);
    if (c < 15) {
      const float* ap2 = ap + (c + 1) * 32;
      *(float4*)&a8[0] = *(const float4*)(ap2);
      *(float4*)&a8[4] = *(const float4*)(ap2 + 4);
    }
    Frag ah, alo;
    ah.u4 = H;
    alo.u4 = L;
    const int ko = c * 32 + g * 8;
#pragma unroll
    for (int mm = 0; mm < (KV ? 2 : 1); ++mm) {
      const unsigned short* wb = Whl + ((size_t)((KV ? (1 + mm) : 0) * 2) * 64) * 512;
#pragma unroll
      for (int nf = 0; nf < 4; ++nf) {
        Frag bh, bl;
        bh.u4 = *(const uint4*)(wb + ((size_t)(nf * 16 + li)) * 512 + ko);
        bl.u4 = *(const uint4*)(wb + ((size_t)(64 + nf * 16 + li)) * 512 + ko);
        const int ai = mm * 4 + nf;
        acc[ai] = __builtin_amdgcn_mfma_f32_16x16x32_bf16(ah.v, bh.v, acc[ai], 0, 0, 0);
        acc[ai] = __builtin_amdgcn_mfma_f32_16x16x32_bf16(alo.v, bh.v, acc[ai], 0, 0, 0);
        acc[ai] = __builtin_amdgcn_mfma_f32_16x16x32_bf16(ah.v, bl.v, acc[ai], 0, 0, 0);
      }
    }
  }

  // epilogue: C row = browbase + r, col = nf*16 + li
  const int browbase = r0g + wi * 16 + g * 4;
  if (KV) {
    float mk[4];
#pragma unroll
    for (int r = 0; r < 4; ++r) mk[r] = maskp[browbase + r];
#pragma unroll
    for (int nf = 0; nf < 4; ++nf)
#pragma unroll
      for (int r = 0; r < 4; ++r)
        Kb[(size_t)(browbase + r) * 64 + nf * 16 + li] = f2bf(acc[nf][r] * mk[r]);
    const int bidx = r0g >> 12;
    const int sbase = (r0g & 4095) + wi * 16 + g * 4;
#pragma unroll
    for (int nf = 0; nf < 4; ++nf) {
      const unsigned int u0 = cvtpk(acc[4 + nf][0] * mk[0], acc[4 + nf][1] * mk[1]);
      const unsigned int u1 = cvtpk(acc[4 + nf][2] * mk[2], acc[4 + nf][3] * mk[3]);
      const ull v = (ull)u0 | ((ull)u1 << 32);
      *(ull*)(Vt + ((size_t)(bidx * 64 + nf * 16 + li)) * SS + sbase) = v;
    }
  } else {
    // zero x-rows give exactly-zero Q rows; mask multiply unnecessary
#pragma unroll
    for (int nf = 0; nf < 4; ++nf)
#pragma unroll
      for (int r = 0; r < 4; ++r)
        Qb[(size_t)(browbase + r) * 64 + nf * 16 + li] = f2bf(acc[nf][r]);
  }
}

// ---------------------------------------------------------------------------
// len_kernel: lengths[b] = #{k : dot(Q[b,0,:], K[b,k,:]) != 0}
// ---------------------------------------------------------------------------
__global__ __launch_bounds__(256) void len_kernel(
    const unsigned short* __restrict__ Qb,
    const unsigned short* __restrict__ Kb,
    unsigned int* __restrict__ lenp)
{
  __shared__ float q0row[64];
  const int t = threadIdx.x;
  const int b = blockIdx.y;
  if (t < 64) q0row[t] = bf2f(Qb[(size_t)b * SS * 64 + t]);
  __syncthreads();
  const int k = blockIdx.x * 256 + t;
  const uint4* kr = (const uint4*)(Kb + ((size_t)(b * SS + k)) * 64);
  float acc = 0.f;
#pragma unroll
  for (int j = 0; j < 8; ++j) {
    uint4 u = kr[j];
    unsigned int w[4] = {u.x, u.y, u.z, u.w};
#pragma unroll
    for (int q = 0; q < 4; ++q) {
      acc = fmaf(q0row[j * 8 + q * 2],     __uint_as_float(w[q] << 16), acc);
      acc = fmaf(q0row[j * 8 + q * 2 + 1], __uint_as_float(w[q] & 0xFFFF0000u), acc);
    }
  }
  unsigned long long bal = __ballot(acc != 0.0f);
  if ((t & 63) == 0) atomicAdd(&lenp[b], (unsigned int)__popcll(bal));
}

// ---------------------------------------------------------------------------
// attn tile body. K from swizzled LDS; V direct from global (L2-hot Vt).
// ---------------------------------------------------------------------------
template <bool MASKED>
__device__ __forceinline__ void tile_body(
    const unsigned int* ksb, const unsigned short* vtb, unsigned int* prow,
    const Frag& qf0, const Frag& qf1, f32x4* O, float& m_r, float& l_r,
    int l, int g, int li, int lim)
{
  // S^T = K Q^T : lane owns q = li; keys kk = a*16 + g*4 + r (log2 units)
  f32x4 acc[4] = {};
#pragma unroll
  for (int f = 0; f < 2; ++f) {
    const bf16x8 qv = f ? qf1.v : qf0.v;
    const int oc = f * 4 + g;
#pragma unroll
    for (int a = 0; a < 4; ++a) {
      const int krow = a * 16 + li;
      Frag kf;
      kf.u4 = *(const uint4*)&ksb[krow * 32 + ((oc ^ (krow & 7)) << 2)];
      acc[a] = __builtin_amdgcn_mfma_f32_16x16x32_bf16(kf.v, qv, acc[a], 0, 0, 0);
    }
  }

  float tm = -1e30f;
#pragma unroll
  for (int a = 0; a < 4; ++a)
#pragma unroll
    for (int r = 0; r < 4; ++r) {
      float v = acc[a][r];
      if (MASKED) v = (a * 16 + (g << 2) + r < lim) ? v : -1e30f;
      acc[a][r] = v;
      tm = fmaxf(tm, v);
    }
  if (__any(tm > m_r + 8.f)) {          // defer-max: rarely taken
    float tq = fmaxf(tm, __shfl_xor(tm, 16));
    tq = fmaxf(tq, __shfl_xor(tq, 32));
    const float nm = fmaxf(m_r, tq);
    const float al = exp2f(m_r - nm);
    m_r = nm;
    l_r *= al;
    float alq[4];
#pragma unroll
    for (int r = 0; r < 4; ++r) alq[r] = __shfl(al, (l & 48) | (g << 2) | r);
#pragma unroll
    for (int o4 = 0; o4 < 4; ++o4)
#pragma unroll
      for (int r = 0; r < 4; ++r) O[o4][r] *= alq[r];
  }
  float rs = 0.f;
#pragma unroll
  for (int a = 0; a < 4; ++a)
#pragma unroll
    for (int r = 0; r < 4; ++r) {
      const float e = exp2f(acc[a][r] - m_r);
      acc[a][r] = e;
      rs += e;
    }
  rs += __shfl_xor(rs, 16);
  rs += __shfl_xor(rs, 32);
  l_r += rs;

  // P -> per-wave LDS (wave-synchronous re-layout C->A), then O += P V
#pragma unroll
  for (int a = 0; a < 4; ++a) {
    prow[a * 8 + g * 2]     = cvtpk(acc[a][0], acc[a][1]);
    prow[a * 8 + g * 2 + 1] = cvtpk(acc[a][2], acc[a][3]);
  }
#pragma unroll
  for (int f = 0; f < 2; ++f) {
    Frag pf;
    pf.u4 = *(const uint4*)&prow[f * 16 + g * 4];
    const int oc = f * 4 + g;
#pragma unroll
    for (int o4 = 0; o4 < 4; ++o4) {
      Frag vf;
      vf.u4 = *(const uint4*)(vtb + (size_t)(o4 * 16 + li) * SS + oc * 8);
      O[o4] = __builtin_amdgcn_mfma_f32_16x16x32_bf16(pf.v, vf.v, O[o4], 0, 0, 0);
    }
  }
}

// ---------------------------------------------------------------------------
// attn_kernel: flash attention, swapped-QK^T, 8 waves x 16q, KV tiles 64.
// K via global_load_lds (pre-swizzled src, 1 gl16/wave/tile, dbuf + counted
// vmcnt); V direct from global. LDS 34KB -> 4 blocks/CU.
// ---------------------------------------------------------------------------
__global__ __launch_bounds__(512, 8) void attn_kernel(
    const unsigned short* __restrict__ Qb,
    const unsigned short* __restrict__ Kb,
    const unsigned short* __restrict__ Vt,
    const unsigned int* __restrict__ lenp,
    float* __restrict__ Op, float* __restrict__ mlp, int kvChunk)
{
  __shared__ __align__(16) unsigned int ks[2][2048];   // [64 key][64 d] bf16, swz
  __shared__ __align__(16) unsigned int ps[8 * 16 * 36];

  const int t  = threadIdx.x;
  const int l  = t & 63;
  const int wi = t >> 6;
  const int g  = l >> 4;
  const int li = l & 15;
  const int b  = blockIdx.z;
  const int sp = blockIdx.y;
  const int q0 = blockIdx.x * 128;

  const unsigned int len = lenp[b];
  const int kvS = sp * kvChunk;
  const int kvE = min((int)len, kvS + kvChunk);
  int rem = kvE - kvS; if (rem < 0) rem = 0;
  const int NF = rem >> 6;
  const int NT = NF + ((rem & 63) ? 1 : 0);

  Frag qf0, qf1;
  {
    const uint4* qg = (const uint4*)(Qb + ((size_t)(b * SS + q0 + wi * 16 + li)) * 64);
    qf0.u4 = qg[g];
    qf1.u4 = qg[4 + g];
  }

  f32x4 O[4] = {};
  float m_r = 0.f, l_r = 0.f;   // defer-max reference starts at 0

  const int srow = wi * 8 + (l >> 3);   // this wave's 8 K-rows
  const int sch = l & 7;
  auto issue = [&](int key0, int bufsel) {
    gl16(Kb + ((size_t)(b * SS + key0 + srow)) * 64 + ((sch ^ (srow & 7)) << 3),
         &ks[bufsel][wi * 256]);
  };

  const unsigned short* vtbase = Vt + (size_t)b * 64 * SS;
  unsigned int* prow = &ps[(wi * 16 + li) * 36];
  int cur = 0;
  if (NT > 0) issue(kvS, 0);
  for (int tix = 0; tix < NT; ++tix) {
    const int key0 = kvS + (tix << 6);
    if (tix + 1 < NT) {
      issue(key0 + 64, cur ^ 1);
      WAITVM(1);
    } else {
      WAITVM(0);
    }
    __builtin_amdgcn_s_barrier();
    __builtin_amdgcn_sched_barrier(0);
    const int lim = kvE - key0;
    if (tix < NF)
      tile_body<false>(&ks[cur][0], vtbase + key0, prow, qf0, qf1, O, m_r, l_r, l, g, li, lim);
    else
      tile_body<true>(&ks[cur][0], vtbase + key0, prow, qf0, qf1, O, m_r, l_r, l, g, li, lim);
    __builtin_amdgcn_s_barrier();   // readers done before next issue overwrites
    cur ^= 1;
  }

  // partial epilogue (unnormalized)
  const int qrow = q0 + wi * 16;
  if (g == 0) {
    mlp[(size_t)sp * 2 * BS + b * SS + qrow + li] = m_r;
    mlp[(size_t)sp * 2 * BS + BS + b * SS + qrow + li] = l_r;
  }
  const size_t obase = (size_t)sp * BS * 64;
#pragma unroll
  for (int o4 = 0; o4 < 4; ++o4)
#pragma unroll
    for (int r = 0; r < 4; ++r)
      Op[obase + ((size_t)(b * SS + qrow + (g << 2) + r)) * 64 + o4 * 16 + li] = O[o4][r];
}

// ---------------------------------------------------------------------------
// combine_kernel<NS>: merge kv-split partials, normalize, apply query mask.
// ---------------------------------------------------------------------------
template <int NS>
__global__ __launch_bounds__(256) void combine_kernel(
    const float* __restrict__ Op, const float* __restrict__ mlp,
    const float* __restrict__ maskp, float* __restrict__ out)
{
  const int i4 = blockIdx.x * 256 + threadIdx.x;
  const int e0 = i4 * 4;
  const int row = e0 >> 6;
  float ms[NS], lsv[NS];
#pragma unroll
  for (int s = 0; s < NS; ++s) {
    ms[s] = mlp[(size_t)s * 2 * BS + row];
    lsv[s] = mlp[(size_t)s * 2 * BS + BS + row];
  }
  float M = -1e30f;
#pragma unroll
  for (int s = 0; s < NS; ++s)
    if (lsv[s] > 0.f) M = fmaxf(M, ms[s]);
  float4 num = {0.f, 0.f, 0.f, 0.f};
  float den = 0.f;
#pragma unroll
  for (int s = 0; s < NS; ++s) {
    if (lsv[s] > 0.f) {
      const float w = exp2f(ms[s] - M);
      const float4 o = *(const float4*)(Op + (size_t)s * BS * 64 + e0);
      num.x += w * o.x; num.y += w * o.y; num.z += w * o.z; num.w += w * o.w;
      den += w * lsv[s];
    }
  }
  const float sc = (den > 0.f) ? maskp[row] / den : 0.f;
  float4 r = {num.x * sc, num.y * sc, num.z * sc, num.w * sc};
  *(float4*)(out + e0) = r;
}

// ---------------------------------------------------------------------------
extern "C" void kernel_launch(void* const* d_in, const int* in_sizes, int n_in,
                              void* d_out, int out_size, void* d_ws, size_t ws_size,
                              hipStream_t stream) {
  const float* x   = (const float*)d_in[0];
  const float* ctx = (const float*)d_in[1];
  const float* Wq  = (const float*)d_in[2];
  const float* Wk  = (const float*)d_in[3];
  const float* Wv  = (const float*)d_in[4];
  float* out = (float*)d_out;

  char* ws = (char*)d_ws;
  unsigned short* Qb = (unsigned short*)(ws);                    // 2MB (scale folded)
  unsigned short* Kb = (unsigned short*)(ws + 2097152);          // 2MB
  unsigned short* Vt = (unsigned short*)(ws + 4194304);          // 2MB [B][64][S]
  float* maskp       = (float*)(ws + 6291456);                   // 64KB
  unsigned int* lenp = (unsigned int*)(ws + 6356992);            // 256B
  unsigned short* Whl = (unsigned short*)(ws + 6357248);         // 384KB pre-split W
  const size_t base = 6357248ull + 393216ull;                    // 6750464

  const size_t sOp = 4194304ull, sMl = 131072ull;
  int nsplit = (ws_size >= base + 8 * (sOp + sMl)) ? 8
             : (ws_size >= base + 4 * (sOp + sMl)) ? 4
             : (ws_size >= base + 2 * (sOp + sMl)) ? 2 : 1;

  float* Op  = (float*)(ws + base);
  float* mlp = (float*)(ws + base + (size_t)nsplit * sOp);

  hipMemsetAsync(lenp, 0, 16, stream);
  prep_w<<<dim3(3, 16), 256, 0, stream>>>(Wq, Wk, Wv, Whl);
  proj_kernel<0><<<dim3(BS / 32), 128, 0, stream>>>(x, ctx, Whl, maskp, Qb, Kb, Vt);
  mask_kernel<<<dim3(BS / 4), 256, 0, stream>>>(x, maskp);
  proj_kernel<1><<<dim3(BS / 32), 128, 0, stream>>>(x, ctx, Whl, maskp, Qb, Kb, Vt);
  len_kernel<<<dim3(16, 4), 256, 0, stream>>>(Qb, Kb, lenp);
  const int kvChunk = SS / nsplit;
  attn_kernel<<<dim3(SS / 128, nsplit, BB), 512, 0, stream>>>(Qb, Kb, Vt, lenp, Op, mlp, kvChunk);
  if (nsplit == 8)      combine_kernel<8><<<dim3(BS * 64 / 1024), 256, 0, stream>>>(Op, mlp, maskp, out);
  else if (nsplit == 4) combine_kernel<4><<<dim3(BS * 64 / 1024), 256, 0, stream>>>(Op, mlp, maskp, out);
  else if (nsplit == 2) combine_kernel<2><<<dim3(BS * 64 / 1024), 256, 0, stream>>>(Op, mlp, maskp, out);
  else                  combine_kernel<1><<<dim3(BS * 64 / 1024), 256, 0, stream>>>(Op, mlp, maskp, out);
}

// Round 5
// 212.235 us; speedup vs baseline: 1.4795x; 1.4795x over previous
//
#include <hip/hip_runtime.h>

// decoderHead: B=4, S=4096, E=512, DK=64, fp32 I/O.
constexpr int BB = 4;
constexpr int SS = 4096;
constexpr int EE = 512;
constexpr int BS = BB * SS;

typedef __attribute__((ext_vector_type(8))) short bf16x8;
typedef __attribute__((ext_vector_type(4))) float f32x4;
typedef unsigned long long ull;

union Frag {
  uint4 u4;
  unsigned int u[4];
  bf16x8 v;
};

__device__ __forceinline__ unsigned short f2bf(float f) {
  unsigned int u = __float_as_uint(f);
  unsigned int r = u + 0x7FFFu + ((u >> 16) & 1u);   // RNE
  return (unsigned short)(r >> 16);
}
__device__ __forceinline__ float bf2f(unsigned short h) {
  return __uint_as_float(((unsigned int)h) << 16);
}
__device__ __forceinline__ unsigned int cvtpk(float a, float b) {
  unsigned int r;
  asm("v_cvt_pk_bf16_f32 %0, %1, %2" : "=v"(r) : "v"(a), "v"(b));
  return r;  // lo = bf16(a), hi = bf16(b)
}
// global -> LDS direct (16B/lane). Dest wave-uniform base; src per-lane.
__device__ __forceinline__ void gl16(const unsigned short* g, unsigned int* l) {
  __builtin_amdgcn_global_load_lds(
      (const __attribute__((address_space(1))) unsigned int*)(size_t)g,
      (__attribute__((address_space(3))) unsigned int*)(unsigned int)(size_t)l,
      16, 0, 0);
}
#define WAITVM(n) asm volatile("s_waitcnt vmcnt(" #n ")" ::: "memory")

// ---------------------------------------------------------------------------
// prep_kernel: blocks 0..47: W transpose+scale -> Wb[mat][n=64][k=512] bf16
// (Q-scale log2(e)/8 folded into mat 0). Blocks 48..: pad-mask from x.
// ---------------------------------------------------------------------------
__global__ __launch_bounds__(256) void prep_kernel(
    const float* __restrict__ x, const float* __restrict__ Wq,
    const float* __restrict__ Wk, const float* __restrict__ Wv,
    unsigned short* __restrict__ Wb, float* __restrict__ maskp) {
  const int bx = blockIdx.x;
  const int t = threadIdx.x;
  if (bx < 48) {
    const int m = bx >> 4, ng = bx & 15;
    const int n = ng * 4 + (t >> 6), kl = t & 63;
    const float* W = (m == 0) ? Wq : (m == 1) ? Wk : Wv;
    const float sc = (m == 0) ? 0.18033688011112042f : 1.0f;
#pragma unroll
    for (int kc = 0; kc < 8; ++kc) {
      const int k = kc * 64 + kl;
      Wb[((size_t)(m * 64 + n)) * 512 + k] = f2bf(W[(size_t)k * 64 + n] * sc);
    }
  } else {
    const int row = (bx - 48) * 4 + (t >> 6);
    const int l = t & 63;
    const uint4* xr = (const uint4*)(x + (size_t)row * EE) + l;
    uint4 a = xr[0], b2 = xr[64];
    unsigned int o = (a.x | a.y | a.z | a.w | b2.x | b2.y | b2.z | b2.w) << 1;
    bool nz = __any(o != 0u);
    if (l == 0) maskp[row] = nz ? 1.0f : 0.0f;
  }
}

// ---------------------------------------------------------------------------
// proj_kernel: register-only bf16 MFMA GEMM (no LDS, no barriers).
// blockIdx.y==0: Q = x@Wq' (scale folded; zero rows stay zero -> no mask);
// blockIdx.y==1: K = (ctx@Wk)*mask, V = (ctx@Wv)*mask -> Vt[b][d][s].
// Block 128 thr = 2 waves x 16 rows; A reg-dbuf from global; B from L1-hot Wb.
// ---------------------------------------------------------------------------
__global__ __launch_bounds__(128) void proj_kernel(
    const float* __restrict__ x, const float* __restrict__ ctx,
    const unsigned short* __restrict__ Wb, const float* __restrict__ maskp,
    unsigned short* __restrict__ Qb, unsigned short* __restrict__ Kb,
    unsigned short* __restrict__ Vt)
{
  const int t = threadIdx.x;
  const int l = t & 63, wi = t >> 6, g = l >> 4, li = l & 15;
  const int kv = blockIdx.y;
  const int r0g = blockIdx.x * 32;
  const int row = r0g + wi * 16 + li;

  const float* A = kv ? ctx : x;
  const float* ap = A + (size_t)row * EE;

  f32x4 acc[8] = {};
  float4 a0 = *(const float4*)(ap + g * 8);
  float4 a1 = *(const float4*)(ap + g * 8 + 4);

  const unsigned short* wb1 = Wb + (size_t)(kv ? 64 : 0) * 512;
  const unsigned short* wb2 = Wb + (size_t)128 * 512;

  for (int c = 0; c < 16; ++c) {
    Frag af;
    af.u[0] = cvtpk(a0.x, a0.y);
    af.u[1] = cvtpk(a0.z, a0.w);
    af.u[2] = cvtpk(a1.x, a1.y);
    af.u[3] = cvtpk(a1.z, a1.w);
    if (c < 15) {
      const float* ap2 = ap + (c + 1) * 32 + g * 8;
      a0 = *(const float4*)ap2;
      a1 = *(const float4*)(ap2 + 4);
    }
    const int ko = c * 32 + g * 8;
#pragma unroll
    for (int nf = 0; nf < 4; ++nf) {
      Frag bfr;
      bfr.u4 = *(const uint4*)(wb1 + ((size_t)(nf * 16 + li)) * 512 + ko);
      acc[nf] = __builtin_amdgcn_mfma_f32_16x16x32_bf16(af.v, bfr.v, acc[nf], 0, 0, 0);
    }
    if (kv) {
#pragma unroll
      for (int nf = 0; nf < 4; ++nf) {
        Frag bfr;
        bfr.u4 = *(const uint4*)(wb2 + ((size_t)(nf * 16 + li)) * 512 + ko);
        acc[4 + nf] = __builtin_amdgcn_mfma_f32_16x16x32_bf16(af.v, bfr.v, acc[4 + nf], 0, 0, 0);
      }
    }
  }

  // epilogue: C row = browbase + r, col = nf*16 + li
  const int browbase = r0g + wi * 16 + g * 4;
  if (!kv) {
#pragma unroll
    for (int nf = 0; nf < 4; ++nf)
#pragma unroll
      for (int r = 0; r < 4; ++r)
        Qb[(size_t)(browbase + r) * 64 + nf * 16 + li] = f2bf(acc[nf][r]);
  } else {
    float mk[4];
#pragma unroll
    for (int r = 0; r < 4; ++r) mk[r] = maskp[browbase + r];
#pragma unroll
    for (int nf = 0; nf < 4; ++nf)
#pragma unroll
      for (int r = 0; r < 4; ++r)
        Kb[(size_t)(browbase + r) * 64 + nf * 16 + li] = f2bf(acc[nf][r] * mk[r]);
    const int bidx = r0g >> 12;
    const int sbase = (r0g & 4095) + wi * 16 + g * 4;
#pragma unroll
    for (int nf = 0; nf < 4; ++nf) {
      const unsigned int u0 = cvtpk(acc[4 + nf][0] * mk[0], acc[4 + nf][1] * mk[1]);
      const unsigned int u1 = cvtpk(acc[4 + nf][2] * mk[2], acc[4 + nf][3] * mk[3]);
      const ull v = (ull)u0 | ((ull)u1 << 32);
      *(ull*)(Vt + ((size_t)(bidx * 64 + nf * 16 + li)) * SS + sbase) = v;
    }
  }
}

// ---------------------------------------------------------------------------
// len_kernel: one 1024-thr block per batch; no atomics (plain store).
// lengths[b] = #{k : dot(Q[b,0,:], K[b,k,:]) != 0}
// ---------------------------------------------------------------------------
__global__ __launch_bounds__(1024) void len_kernel(
    const unsigned short* __restrict__ Qb,
    const unsigned short* __restrict__ Kb,
    unsigned int* __restrict__ lenp)
{
  __shared__ float q0[64];
  __shared__ unsigned int part[16];
  const int t = threadIdx.x;
  const int b = blockIdx.x;
  if (t < 64) q0[t] = bf2f(Qb[(size_t)b * SS * 64 + t]);
  __syncthreads();
  unsigned int cnt = 0;
#pragma unroll
  for (int j = 0; j < 4; ++j) {
    const int k = t * 4 + j;
    const uint4* kr = (const uint4*)(Kb + ((size_t)(b * SS + k)) * 64);
    float acc = 0.f;
#pragma unroll
    for (int j8 = 0; j8 < 8; ++j8) {
      uint4 u = kr[j8];
      unsigned int w[4] = {u.x, u.y, u.z, u.w};
#pragma unroll
      for (int q = 0; q < 4; ++q) {
        acc = fmaf(q0[j8 * 8 + q * 2],     __uint_as_float(w[q] << 16), acc);
        acc = fmaf(q0[j8 * 8 + q * 2 + 1], __uint_as_float(w[q] & 0xFFFF0000u), acc);
      }
    }
    cnt += (acc != 0.f) ? 1u : 0u;
  }
#pragma unroll
  for (int off = 1; off < 64; off <<= 1) cnt += __shfl_xor(cnt, off);
  if ((t & 63) == 0) part[t >> 6] = cnt;
  __syncthreads();
  if (t == 0) {
    unsigned int s = 0;
#pragma unroll
    for (int i = 0; i < 16; ++i) s += part[i];
    lenp[b] = s;
  }
}

// ---------------------------------------------------------------------------
// attn tile body (r3-verified). K,V from swizzled LDS; P via per-wave LDS.
// ---------------------------------------------------------------------------
template <bool MASKED>
__device__ __forceinline__ void tile_body(
    const unsigned int* ksb, const unsigned int* vsb, unsigned int* prow,
    const Frag& qf0, const Frag& qf1, f32x4* O, float& m_r, float& l_r,
    int l, int g, int li, int lim)
{
  // S^T = K Q^T : lane owns q = li; keys kk = a*16 + g*4 + r (log2 units)
  f32x4 acc[4] = {};
#pragma unroll
  for (int f = 0; f < 2; ++f) {
    const bf16x8 qv = f ? qf1.v : qf0.v;
    const int oc = f * 4 + g;
#pragma unroll
    for (int a = 0; a < 4; ++a) {
      const int krow = a * 16 + li;
      Frag kf;
      kf.u4 = *(const uint4*)&ksb[krow * 32 + ((oc ^ (krow & 7)) << 2)];
      acc[a] = __builtin_amdgcn_mfma_f32_16x16x32_bf16(kf.v, qv, acc[a], 0, 0, 0);
    }
  }

  float tm = -1e30f;
#pragma unroll
  for (int a = 0; a < 4; ++a)
#pragma unroll
    for (int r = 0; r < 4; ++r) {
      float v = acc[a][r];
      if (MASKED) v = (a * 16 + (g << 2) + r < lim) ? v : -1e30f;
      acc[a][r] = v;
      tm = fmaxf(tm, v);
    }
  if (__any(tm > m_r + 8.f)) {          // defer-max: rarely taken
    float tq = fmaxf(tm, __shfl_xor(tm, 16));
    tq = fmaxf(tq, __shfl_xor(tq, 32));
    const float nm = fmaxf(m_r, tq);
    const float al = exp2f(m_r - nm);
    m_r = nm;
    l_r *= al;
    float alq[4];
#pragma unroll
    for (int r = 0; r < 4; ++r) alq[r] = __shfl(al, (l & 48) | (g << 2) | r);
#pragma unroll
    for (int o4 = 0; o4 < 4; ++o4)
#pragma unroll
      for (int r = 0; r < 4; ++r) O[o4][r] *= alq[r];
  }
  float rs = 0.f;
#pragma unroll
  for (int a = 0; a < 4; ++a)
#pragma unroll
    for (int r = 0; r < 4; ++r) {
      const float e = exp2f(acc[a][r] - m_r);
      acc[a][r] = e;
      rs += e;
    }
  rs += __shfl_xor(rs, 16);
  rs += __shfl_xor(rs, 32);
  l_r += rs;

  // P -> per-wave LDS (wave-synchronous re-layout C->A), then O += P V
#pragma unroll
  for (int a = 0; a < 4; ++a) {
    prow[a * 8 + g * 2]     = cvtpk(acc[a][0], acc[a][1]);
    prow[a * 8 + g * 2 + 1] = cvtpk(acc[a][2], acc[a][3]);
  }
#pragma unroll
  for (int f = 0; f < 2; ++f) {
    Frag pf;
    pf.u4 = *(const uint4*)&prow[f * 16 + g * 4];
    const int oc = f * 4 + g;
#pragma unroll
    for (int o4 = 0; o4 < 4; ++o4) {
      const int vrow = o4 * 16 + li;
      Frag vf;
      vf.u4 = *(const uint4*)&vsb[vrow * 32 + ((oc ^ (vrow & 7)) << 2)];
      O[o4] = __builtin_amdgcn_mfma_f32_16x16x32_bf16(pf.v, vf.v, O[o4], 0, 0, 0);
    }
  }
}

// ---------------------------------------------------------------------------
// attn_kernel (r3-verified): swapped-QK^T flash, NW waves x 16q, KV tiles 64.
// K,V via global_load_lds (pre-swizzled src), dbuf + counted vmcnt.
// ---------------------------------------------------------------------------
template <int NW>
__global__ __launch_bounds__(NW * 64, (NW == 8) ? 4 : 3) void attn_kernel(
    const unsigned short* __restrict__ Qb,
    const unsigned short* __restrict__ Kb,
    const unsigned short* __restrict__ Vt,
    const unsigned int* __restrict__ lenp,
    float* __restrict__ Op, float* __restrict__ mlp, int kvChunk)
{
  __shared__ __align__(16) unsigned int ks[2][2048];   // [64 key][64 d] bf16, swz
  __shared__ __align__(16) unsigned int vs[2][2048];   // [64 d][64 key] bf16, swz
  __shared__ __align__(16) unsigned int ps[NW * 16 * 36];

  constexpr int SPW = 16 / NW;   // 1KB staging segments per wave

  const int t  = threadIdx.x;
  const int l  = t & 63;
  const int wi = t >> 6;
  const int g  = l >> 4;
  const int li = l & 15;
  const int b  = blockIdx.z;
  const int sp = blockIdx.y;
  const int q0 = blockIdx.x * (NW * 16);

  const unsigned int len = lenp[b];
  const int kvS = sp * kvChunk;
  const int kvE = min((int)len, kvS + kvChunk);
  int rem = kvE - kvS; if (rem < 0) rem = 0;
  const int NF = rem >> 6;
  const int NT = NF + ((rem & 63) ? 1 : 0);

  Frag qf0, qf1;
  {
    const uint4* qg = (const uint4*)(Qb + ((size_t)(b * SS + q0 + wi * 16 + li)) * 64);
    qf0.u4 = qg[g];
    qf1.u4 = qg[4 + g];
  }

  f32x4 O[4] = {};
  float m_r = 0.f, l_r = 0.f;   // defer-max reference starts at 0

  const int srow8 = l >> 3;     // 0..7 within segment
  const int sch = l & 7;
  auto issue = [&](int key0, int bufsel) {
#pragma unroll
    for (int s2 = 0; s2 < SPW; ++s2) {
      const int seg = wi * SPW + s2;   // 0..15: first 8 = K, last 8 = V
      const int s8 = seg & 7;
      const int row = s8 * 8 + srow8;
      if (seg < 8) {
        gl16(Kb + ((size_t)(b * SS + key0 + row)) * 64 + ((sch ^ (row & 7)) << 3),
             &ks[bufsel][s8 * 256]);
      } else {
        gl16(Vt + ((size_t)(b * 64 + row)) * SS + key0 + ((sch ^ (row & 7)) << 3),
             &vs[bufsel][s8 * 256]);
      }
    }
  };

  unsigned int* prow = &ps[(wi * 16 + li) * 36];
  int cur = 0;
  if (NT > 0) issue(kvS, 0);
  for (int tix = 0; tix < NT; ++tix) {
    const int key0 = kvS + (tix << 6);
    if (tix + 1 < NT) {
      issue(key0 + 64, cur ^ 1);
      if constexpr (NW == 8) { WAITVM(2); } else { WAITVM(4); }
    } else {
      WAITVM(0);
    }
    __builtin_amdgcn_s_barrier();
    __builtin_amdgcn_sched_barrier(0);
    const int lim = kvE - key0;
    if (tix < NF)
      tile_body<false>(&ks[cur][0], &vs[cur][0], prow, qf0, qf1, O, m_r, l_r, l, g, li, lim);
    else
      tile_body<true>(&ks[cur][0], &vs[cur][0], prow, qf0, qf1, O, m_r, l_r, l, g, li, lim);
    __builtin_amdgcn_s_barrier();   // readers done before next issue overwrites
    cur ^= 1;
  }

  // partial epilogue (unnormalized)
  const int qrow = q0 + wi * 16;
  if (g == 0) {
    mlp[(size_t)sp * 2 * BS + b * SS + qrow + li] = m_r;
    mlp[(size_t)sp * 2 * BS + BS + b * SS + qrow + li] = l_r;
  }
  const size_t obase = (size_t)sp * BS * 64;
#pragma unroll
  for (int o4 = 0; o4 < 4; ++o4)
#pragma unroll
    for (int r = 0; r < 4; ++r)
      Op[obase + ((size_t)(b * SS + qrow + (g << 2) + r)) * 64 + o4 * 16 + li] = O[o4][r];
}

// ---------------------------------------------------------------------------
// combine_kernel<NS>: merge kv-split partials, normalize, apply query mask.
// ---------------------------------------------------------------------------
template <int NS>
__global__ __launch_bounds__(256) void combine_kernel(
    const float* __restrict__ Op, const float* __restrict__ mlp,
    const float* __restrict__ maskp, float* __restrict__ out)
{
  const int i4 = blockIdx.x * 256 + threadIdx.x;
  const int e0 = i4 * 4;
  const int row = e0 >> 6;
  float ms[NS], lsv[NS];
#pragma unroll
  for (int s = 0; s < NS; ++s) {
    ms[s] = mlp[(size_t)s * 2 * BS + row];
    lsv[s] = mlp[(size_t)s * 2 * BS + BS + row];
  }
  float M = -1e30f;
#pragma unroll
  for (int s = 0; s < NS; ++s)
    if (lsv[s] > 0.f) M = fmaxf(M, ms[s]);
  float4 num = {0.f, 0.f, 0.f, 0.f};
  float den = 0.f;
#pragma unroll
  for (int s = 0; s < NS; ++s) {
    if (lsv[s] > 0.f) {
      const float w = exp2f(ms[s] - M);
      const float4 o = *(const float4*)(Op + (size_t)s * BS * 64 + e0);
      num.x += w * o.x; num.y += w * o.y; num.z += w * o.z; num.w += w * o.w;
      den += w * lsv[s];
    }
  }
  const float sc = (den > 0.f) ? maskp[row] / den : 0.f;
  float4 r = {num.x * sc, num.y * sc, num.z * sc, num.w * sc};
  *(float4*)(out + e0) = r;
}

// ---------------------------------------------------------------------------
extern "C" void kernel_launch(void* const* d_in, const int* in_sizes, int n_in,
                              void* d_out, int out_size, void* d_ws, size_t ws_size,
                              hipStream_t stream) {
  const float* x   = (const float*)d_in[0];
  const float* ctx = (const float*)d_in[1];
  const float* Wq  = (const float*)d_in[2];
  const float* Wk  = (const float*)d_in[3];
  const float* Wv  = (const float*)d_in[4];
  float* out = (float*)d_out;

  char* ws = (char*)d_ws;
  unsigned short* Qb = (unsigned short*)(ws);                    // 2MB (scale folded)
  unsigned short* Kb = (unsigned short*)(ws + 2097152);          // 2MB
  unsigned short* Vt = (unsigned short*)(ws + 4194304);          // 2MB [B][64][S]
  float* maskp       = (float*)(ws + 6291456);                   // 64KB
  unsigned int* lenp = (unsigned int*)(ws + 6356992);            // 256B
  unsigned short* Wb = (unsigned short*)(ws + 6357248);          // 192KB bf16 W
  const size_t base = 6357248ull + 196608ull;                    // 6553856

  const size_t sOp = 4194304ull, sMl = 131072ull;
  int nsplit = (ws_size >= base + 8 * (sOp + sMl)) ? 8
             : (ws_size >= base + 4 * (sOp + sMl)) ? 4
             : (ws_size >= base + 2 * (sOp + sMl)) ? 2 : 1;

  float* Op  = (float*)(ws + base);
  float* mlp = (float*)(ws + base + (size_t)nsplit * sOp);

  prep_kernel<<<dim3(48 + BS / 4), 256, 0, stream>>>(x, Wq, Wk, Wv, Wb, maskp);
  proj_kernel<<<dim3(BS / 32, 2), 128, 0, stream>>>(x, ctx, Wb, maskp, Qb, Kb, Vt);
  len_kernel<<<dim3(BB), 1024, 0, stream>>>(Qb, Kb, lenp);
  const int kvChunk = SS / nsplit;
  if (nsplit >= 4) {
    attn_kernel<8><<<dim3(SS / 128, nsplit, BB), 512, 0, stream>>>(Qb, Kb, Vt, lenp, Op, mlp, kvChunk);
  } else {
    attn_kernel<4><<<dim3(SS / 64, nsplit, BB), 256, 0, stream>>>(Qb, Kb, Vt, lenp, Op, mlp, kvChunk);
  }
  if (nsplit == 8)      combine_kernel<8><<<dim3(BS * 64 / 1024), 256, 0, stream>>>(Op, mlp, maskp, out);
  else if (nsplit == 4) combine_kernel<4><<<dim3(BS * 64 / 1024), 256, 0, stream>>>(Op, mlp, maskp, out);
  else if (nsplit == 2) combine_kernel<2><<<dim3(BS * 64 / 1024), 256, 0, stream>>>(Op, mlp, maskp, out);
  else                  combine_kernel<1><<<dim3(BS * 64 / 1024), 256, 0, stream>>>(Op, mlp, maskp, out);
}